// Round 1
// 170.393 us; speedup vs baseline: 1.0342x; 1.0342x over previous
//
#include <hip/hip_runtime.h>
#include <hip/hip_bf16.h>

typedef __hip_bfloat16 bf16;
typedef __attribute__((ext_vector_type(8))) short short8_t;
typedef __attribute__((ext_vector_type(4))) short short4_t;
typedef __attribute__((ext_vector_type(4))) float f32x4;

#define B_SZ   2
#define T_SEQ  2048
#define C_DIM  1024
#define NH     16
#define NKV    4
#define HD     64
#define QKVW   1536          // fused QKV row width (1024 Q | 256 K | 256 V)
#define MTOK   (B_SZ * T_SEQ)

#define LOG2_BASE_OVER_32 0.4152410118609203f
#define Q_SCALE 0.1803368801111204f   // 0.125 * log2(e)

__device__ __forceinline__ short f2bs(float f) {
    unsigned u = __float_as_uint(f);
    u += 0x7FFFu + ((u >> 16) & 1u);
    return (short)(u >> 16);
}
__device__ __forceinline__ short f2bs_trunc(float f) {
    return (short)(__float_as_uint(f) >> 16);
}
__device__ __forceinline__ float bs2f(short s) {
    unsigned u = ((unsigned)(unsigned short)s) << 16;
    return __uint_as_float(u);
}
// lane <-> lane^1 exchange, pure VALU (quad_perm [1,0,3,2])
__device__ __forceinline__ float dpp_xor1(float x) {
    return __int_as_float(
        __builtin_amdgcn_update_dpp(0, __float_as_int(x), 0xB1, 0xF, 0xF, true));
}
// bare v_exp_f32 (2^x). libm exp2f adds a denormal-guard wrapper (~8 VALU);
// here inputs are <= +8 or -inf, both exact on the raw instruction.
__device__ __forceinline__ float fast_exp2(float x) {
    float r;
    asm("v_exp_f32 %0, %1" : "=v"(r) : "v"(x));
    return r;
}
// pack hi16(lo), hi16(hi) -> one dword (two bf16, truncating) in 1 v_perm_b32
__device__ __forceinline__ unsigned pack_bf16_trunc(float lo, float hi) {
    return __builtin_amdgcn_perm(__float_as_uint(hi), __float_as_uint(lo),
                                 0x07060302u);
}

// ---------------------------------------------------------------------------
// Fused prep (unchanged): x->bf16, weight transposes, bias concat, RoPE table
// ---------------------------------------------------------------------------
__device__ __forceinline__ void transpose_tile(
    const float* __restrict__ W, short* __restrict__ Wt,
    int K, int N, int n0, int k0, int tid)
{
    __shared__ float tile[32][33];
    int tx = tid & 31, ty = tid >> 5;
    #pragma unroll
    for (int i = 0; i < 4; ++i)
        tile[ty + 8 * i][tx] = W[(size_t)(k0 + ty + 8 * i) * N + n0 + tx];
    __syncthreads();
    #pragma unroll
    for (int i = 0; i < 4; ++i)
        Wt[(size_t)(n0 + ty + 8 * i) * K + k0 + tx] = f2bs(tile[tx][ty + 8 * i]);
}

__global__ __launch_bounds__(256) void prep_kernel(
    const float* __restrict__ x,
    const float* __restrict__ w_q, const float* __restrict__ w_k,
    const float* __restrict__ w_v, const float* __restrict__ w_o,
    const float* __restrict__ b_q, const float* __restrict__ b_k,
    const float* __restrict__ b_v,
    short* __restrict__ Xb, short* __restrict__ Wqkv, short* __restrict__ Wto,
    float* __restrict__ Bqkv, float2* __restrict__ Tab)
{
    int blk = blockIdx.x, tid = threadIdx.x;
    if (blk < 4096) {
        int i = blk * 1024 + tid * 4;
        float4 v = *(const float4*)(x + i);
        short4_t o;
        o[0] = f2bs(v.x); o[1] = f2bs(v.y); o[2] = f2bs(v.z); o[3] = f2bs(v.w);
        *(short4_t*)(Xb + i) = o;
    } else if (blk < 5120) {
        int l = blk - 4096;
        transpose_tile(w_q, Wqkv, C_DIM, C_DIM, (l & 31) * 32, (l >> 5) * 32, tid);
    } else if (blk < 5376) {
        int l = blk - 5120;
        transpose_tile(w_k, Wqkv + (size_t)1024 * C_DIM, C_DIM, 256,
                       (l & 7) * 32, (l >> 3) * 32, tid);
    } else if (blk < 5632) {
        int l = blk - 5376;
        transpose_tile(w_v, Wqkv + (size_t)1280 * C_DIM, C_DIM, 256,
                       (l & 7) * 32, (l >> 3) * 32, tid);
    } else if (blk < 6656) {
        int l = blk - 5632;
        transpose_tile(w_o, Wto, C_DIM, C_DIM, (l & 31) * 32, (l >> 5) * 32, tid);
    } else if (blk < 6662) {
        int i = (blk - 6656) * 256 + tid;
        float v;
        if (i < 1024)      v = b_q[i];
        else if (i < 1280) v = b_k[i - 1024];
        else               v = b_v[i - 1280];
        Bqkv[i] = v;
    } else {
        int idx = (blk - 6662) * 256 + tid;
        int t = idx >> 5, i = idx & 31;
        float ang = (float)t * exp2f(-(float)i * LOG2_BASE_OVER_32);
        Tab[idx] = make_float2(cosf(ang), sinf(ang));
    }
}

// ---------------------------------------------------------------------------
// QKV GEMM, 128x64 tile (BM=128,BN=64,BK=32), double-buffered, 256 thr =
// 4 waves of 64x32. 768 blocks -> 3 blocks/CU. Fused epilogue:
//   n0<1024 (Q): +bias, RoPE, *Q_SCALE; 1024<=n0<1280 (K): +bias, RoPE;
//   n0>=1280 (V): +bias, transpose via LDS -> Vt[d][token].
// ---------------------------------------------------------------------------
__global__ __launch_bounds__(256) void gemm_qkv(
    const short* __restrict__ A, const short* __restrict__ Bt,
    const float* __restrict__ bias, const float2* __restrict__ Tab,
    short* __restrict__ QKVb, short* __restrict__ Vt)
{
    __shared__ __align__(16) short smem[15360];          // 30 KB
    short (*sA)[128][40] = (short(*)[128][40])smem;      // 2 x 128 x 40
    short (*sB)[64][40]  = (short(*)[64][40])(smem + 10240);

    const int K = C_DIM;
    int m0 = blockIdx.y * 128;
    int n0 = blockIdx.x * 64;
    int tid  = threadIdx.x;
    int w    = tid >> 6, lane = tid & 63;
    int quad = lane >> 4, l16 = lane & 15;
    int wm = w & 1, wn = w >> 1;

    f32x4 acc[4][2] = {};

    short8_t ra[2], rb;
    #pragma unroll
    for (int it = 0; it < 2; ++it) {
        int slot = tid + 256 * it, row = slot >> 2, g = (slot & 3) * 8;
        ra[it] = *(const short8_t*)(A + (size_t)(m0 + row) * K + g);
    }
    {
        int row = tid >> 2, g = (tid & 3) * 8;
        rb = *(const short8_t*)(Bt + (size_t)(n0 + row) * K + g);
    }

    int buf = 0;
    for (int k0 = 0; k0 < K; k0 += 32, buf ^= 1) {
        #pragma unroll
        for (int it = 0; it < 2; ++it) {
            int slot = tid + 256 * it, row = slot >> 2, g = (slot & 3) * 8;
            *(short8_t*)&sA[buf][row][g] = ra[it];
        }
        {
            int row = tid >> 2, g = (tid & 3) * 8;
            *(short8_t*)&sB[buf][row][g] = rb;
        }
        if (k0 + 32 < K) {
            #pragma unroll
            for (int it = 0; it < 2; ++it) {
                int slot = tid + 256 * it, row = slot >> 2, g = (slot & 3) * 8;
                ra[it] = *(const short8_t*)(A + (size_t)(m0 + row) * K + k0 + 32 + g);
            }
            int row = tid >> 2, g = (tid & 3) * 8;
            rb = *(const short8_t*)(Bt + (size_t)(n0 + row) * K + k0 + 32 + g);
        }
        __syncthreads();

        short8_t af[4], bfr[2];
        #pragma unroll
        for (int mt = 0; mt < 4; ++mt)
            af[mt] = *(const short8_t*)&sA[buf][wm * 64 + mt * 16 + l16][quad * 8];
        #pragma unroll
        for (int nt = 0; nt < 2; ++nt)
            bfr[nt] = *(const short8_t*)&sB[buf][wn * 32 + nt * 16 + l16][quad * 8];
        #pragma unroll
        for (int mt = 0; mt < 4; ++mt)
            #pragma unroll
            for (int nt = 0; nt < 2; ++nt)
                acc[mt][nt] = __builtin_amdgcn_mfma_f32_16x16x32_bf16(
                    af[mt], bfr[nt], acc[mt][nt], 0, 0, 0);
    }

    if (n0 < 1280) {
        // Q or K: bias + RoPE (+ Q_SCALE for Q)
        float scale = (n0 < 1024) ? Q_SCALE : 1.0f;
        float sgn   = (l16 & 1) ? 1.0f : -1.0f;
        #pragma unroll
        for (int nt = 0; nt < 2; ++nt) {
            int col = n0 + wn * 32 + nt * 16 + l16;
            int ip  = (col & 63) >> 1;
            float bv = bias[col];
            #pragma unroll
            for (int mt = 0; mt < 4; ++mt) {
                #pragma unroll
                for (int r = 0; r < 4; ++r) {
                    int row = m0 + wm * 64 + mt * 16 + quad * 4 + r;
                    float v = acc[mt][nt][r] + bv;
                    float po = dpp_xor1(v);
                    float2 cs = Tab[(row & (T_SEQ - 1)) * 32 + ip];
                    float res = (v * cs.x + sgn * po * cs.y) * scale;
                    QKVb[(size_t)row * QKVW + col] = f2bs(res);
                }
            }
        }
    } else {
        // V: bias + transpose via LDS -> Vt[d][token]
        __syncthreads();
        short (*sT)[136] = (short(*)[136])smem;    // 64 x 136 = 17.4 KB
        #pragma unroll
        for (int nt = 0; nt < 2; ++nt) {
            int col_l = wn * 32 + nt * 16 + l16;   // 0..63
            float bv = bias[n0 + col_l];
            #pragma unroll
            for (int mt = 0; mt < 4; ++mt)
                #pragma unroll
                for (int r = 0; r < 4; ++r)
                    sT[col_l][wm * 64 + mt * 16 + quad * 4 + r] =
                        f2bs(acc[mt][nt][r] + bv);
        }
        __syncthreads();
        int d0 = n0 - 1280;
        #pragma unroll
        for (int it = 0; it < 4; ++it) {
            int slot = tid + 256 * it;             // 64 dims x 16 segs
            int dl = slot >> 4, seg = (slot & 15) * 8;
            *(short8_t*)(Vt + (size_t)(d0 + dl) * MTOK + m0 + seg) =
                *(const short8_t*)&sT[dl][seg];
        }
    }
}

// ---------------------------------------------------------------------------
// O-projection GEMM, 128x64 tile (512 blocks -> 2/CU), fp32 out
// ---------------------------------------------------------------------------
__global__ __launch_bounds__(256) void gemm_mfma_o(
    const short* __restrict__ A, const short* __restrict__ Bt,
    const float* __restrict__ bias, float* __restrict__ C,
    int M, int N, int K)
{
    __shared__ __align__(16) short smem[15360];
    short (*sA)[128][40] = (short(*)[128][40])smem;
    short (*sB)[64][40]  = (short(*)[64][40])(smem + 10240);

    int m0 = blockIdx.y * 128;
    int n0 = blockIdx.x * 64;
    int tid  = threadIdx.x;
    int w    = tid >> 6, lane = tid & 63;
    int quad = lane >> 4, l16 = lane & 15;
    int wm = w & 1, wn = w >> 1;

    f32x4 acc[4][2] = {};

    short8_t ra[2], rb;
    #pragma unroll
    for (int it = 0; it < 2; ++it) {
        int slot = tid + 256 * it, row = slot >> 2, g = (slot & 3) * 8;
        ra[it] = *(const short8_t*)(A + (size_t)(m0 + row) * K + g);
    }
    {
        int row = tid >> 2, g = (tid & 3) * 8;
        rb = *(const short8_t*)(Bt + (size_t)(n0 + row) * K + g);
    }

    int buf = 0;
    for (int k0 = 0; k0 < K; k0 += 32, buf ^= 1) {
        #pragma unroll
        for (int it = 0; it < 2; ++it) {
            int slot = tid + 256 * it, row = slot >> 2, g = (slot & 3) * 8;
            *(short8_t*)&sA[buf][row][g] = ra[it];
        }
        {
            int row = tid >> 2, g = (tid & 3) * 8;
            *(short8_t*)&sB[buf][row][g] = rb;
        }
        if (k0 + 32 < K) {
            #pragma unroll
            for (int it = 0; it < 2; ++it) {
                int slot = tid + 256 * it, row = slot >> 2, g = (slot & 3) * 8;
                ra[it] = *(const short8_t*)(A + (size_t)(m0 + row) * K + k0 + 32 + g);
            }
            int row = tid >> 2, g = (tid & 3) * 8;
            rb = *(const short8_t*)(Bt + (size_t)(n0 + row) * K + k0 + 32 + g);
        }
        __syncthreads();

        short8_t af[4], bfr[2];
        #pragma unroll
        for (int mt = 0; mt < 4; ++mt)
            af[mt] = *(const short8_t*)&sA[buf][wm * 64 + mt * 16 + l16][quad * 8];
        #pragma unroll
        for (int nt = 0; nt < 2; ++nt)
            bfr[nt] = *(const short8_t*)&sB[buf][wn * 32 + nt * 16 + l16][quad * 8];
        #pragma unroll
        for (int mt = 0; mt < 4; ++mt)
            #pragma unroll
            for (int nt = 0; nt < 2; ++nt)
                acc[mt][nt] = __builtin_amdgcn_mfma_f32_16x16x32_bf16(
                    af[mt], bfr[nt], acc[mt][nt], 0, 0, 0);
    }

    #pragma unroll
    for (int mt = 0; mt < 4; ++mt) {
        #pragma unroll
        for (int nt = 0; nt < 2; ++nt) {
            int col = n0 + wn * 32 + nt * 16 + l16;
            float bv = bias[col];
            #pragma unroll
            for (int r = 0; r < 4; ++r) {
                int row = m0 + wm * 64 + mt * 16 + quad * 4 + r;
                C[(size_t)row * N + col] = acc[mt][nt][r] + bv;
            }
        }
    }
}

// ---------------------------------------------------------------------------
// MFMA flash attention v10 = v9 structure (LDS-staged K/Vt, S^T formulation,
// 64-key chunks, per-lane softmax, transposed P via per-wave sP) with the
// VALU fat trimmed:
//   - bare v_exp_f32 instead of libm exp2f (drops the ~8-op denormal guard)
//   - defer-max (THR=8): skip shuffle-reduce + al + O-rescale while the
//     local max stays within 8 of the running max (P bounded by 2^8, fine
//     for bf16/f32); first chunk provably takes the full-update path
//   - per-lane partial l (quad-partial sums); single cross-quad reduce in
//     the epilogue instead of 2 shuffles per chunk
//   - v_perm_b32 pair-pack for P->bf16
//   - s_setprio(1) around MFMA clusters
// ---------------------------------------------------------------------------
__global__ __launch_bounds__(256) void attn_mfma10(
    const short* __restrict__ QKV, const short* __restrict__ Vt,
    short* __restrict__ O)
{
    __shared__ __align__(16) short sK [64][72];
    __shared__ __align__(16) short sVt[64][72];
    __shared__ __align__(16) short sP [4][16][72];

    const int tid  = threadIdx.x;
    const int w    = tid >> 6;
    const int lane = tid & 63;
    const int quad = lane >> 4;
    const int l16  = lane & 15;

    int blk = blockIdx.x;
    int grp = blk & 7;                 // (b,kvh)
    int tq  = 127 - (blk >> 3);        // long tiles first
    int kvh = grp & 3;
    int b   = grp >> 2;
    int h   = kvh * 4 + w;
    int ct  = tq >> 2;
    int tg  = tq * 16 + l16;

    // Q frags (already roped + scaled)
    const short* qptr = QKV + ((size_t)(b * T_SEQ) + tq * 16 + l16) * QKVW + h * HD;
    short8_t qf0 = *(const short8_t*)(qptr + quad * 8);
    short8_t qf1 = *(const short8_t*)(qptr + quad * 8 + 32);

    const short* kbase  = QKV + (size_t)b * T_SEQ * QKVW + 1024 + kvh * HD;
    const short* vtbase = Vt + (size_t)(kvh * HD) * MTOK + b * T_SEQ;

    float m_l = -INFINITY, l_l = 0.f;   // l_l is the QUAD-PARTIAL row sum
    f32x4 oacc[4];
    #pragma unroll
    for (int dt = 0; dt < 4; ++dt) oacc[dt] = (f32x4){0.f, 0.f, 0.f, 0.f};

    const int kkey = tid >> 3, kd = (tid & 7) * 8;
    const int vdim = tid >> 3, vseg = (tid & 7) * 8;

    short8_t kr[2], vr[2];
    #pragma unroll
    for (int it = 0; it < 2; ++it) {
        kr[it] = *(const short8_t*)(kbase + (size_t)(kkey + 32 * it) * QKVW + kd);
        vr[it] = *(const short8_t*)(vtbase + (size_t)(vdim + 32 * it) * MTOK + vseg);
    }

    for (int c = 0; c <= ct; ++c) {
        __syncthreads();
        #pragma unroll
        for (int it = 0; it < 2; ++it) {
            *(short8_t*)&sK [kkey + 32 * it][kd]   = kr[it];
            *(short8_t*)&sVt[vdim + 32 * it][vseg] = vr[it];
        }
        __syncthreads();
        if (c < ct) {
            int jn = (c + 1) * 64;
            #pragma unroll
            for (int it = 0; it < 2; ++it) {
                kr[it] = *(const short8_t*)(kbase + (size_t)(jn + kkey + 32 * it) * QKVW + kd);
                vr[it] = *(const short8_t*)(vtbase + (size_t)(vdim + 32 * it) * MTOK + jn + vseg);
            }
        }

        // S^T = K Q^T : rows = keys 16kt+quad*4+r, col = q = l16
        f32x4 sacc[4];
        __builtin_amdgcn_s_setprio(1);
        #pragma unroll
        for (int kt = 0; kt < 4; ++kt) {
            f32x4 z = {0.f, 0.f, 0.f, 0.f};
            short8_t kf0 = *(const short8_t*)&sK[l16 + 16 * kt][quad * 8];
            short8_t kf1 = *(const short8_t*)&sK[l16 + 16 * kt][quad * 8 + 32];
            z = __builtin_amdgcn_mfma_f32_16x16x32_bf16(kf0, qf0, z, 0, 0, 0);
            z = __builtin_amdgcn_mfma_f32_16x16x32_bf16(kf1, qf1, z, 0, 0, 0);
            sacc[kt] = z;
        }
        __builtin_amdgcn_s_setprio(0);

        if (c == ct) {
            int j0 = c * 64;
            #pragma unroll
            for (int kt = 0; kt < 4; ++kt)
                #pragma unroll
                for (int r = 0; r < 4; ++r)
                    if (j0 + 16 * kt + quad * 4 + r > tg) sacc[kt][r] = -INFINITY;
        }

        // local (quad-partial) max, nested triples -> v_max3
        float v0 = fmaxf(fmaxf(sacc[0][0], sacc[0][1]), fmaxf(sacc[0][2], sacc[0][3]));
        float v1 = fmaxf(fmaxf(sacc[1][0], sacc[1][1]), fmaxf(sacc[1][2], sacc[1][3]));
        float v2 = fmaxf(fmaxf(sacc[2][0], sacc[2][1]), fmaxf(sacc[2][2], sacc[2][3]));
        float v3 = fmaxf(fmaxf(sacc[3][0], sacc[3][1]), fmaxf(sacc[3][2], sacc[3][3]));
        float vloc = fmaxf(fmaxf(v0, v1), fmaxf(v2, v3));

        // defer-max: only do the full (shuffle + rescale) update when some
        // lane's local max exceeds the running max by more than 8.
        // First chunk: m_l = -inf, any finite vloc fails the test -> update.
        if (!__all(vloc <= m_l + 8.0f)) {
            float vmax = fmaxf(vloc, __shfl_xor(vloc, 16));
            vmax = fmaxf(vmax, __shfl_xor(vmax, 32));
            float mnew = fmaxf(m_l, vmax);
            float al = fast_exp2(m_l - mnew);      // exp2(-inf)=0 on chunk 0
            m_l = mnew;
            l_l *= al;
            #pragma unroll
            for (int r = 0; r < 4; ++r) {
                float alr = __shfl(al, quad * 4 + r);
                #pragma unroll
                for (int dt = 0; dt < 4; ++dt) oacc[dt][r] *= alr;
            }
        }

        float psum = 0.f;
        #pragma unroll
        for (int kt = 0; kt < 4; ++kt) {
            float p0 = fast_exp2(sacc[kt][0] - m_l);
            float p1 = fast_exp2(sacc[kt][1] - m_l);
            float p2 = fast_exp2(sacc[kt][2] - m_l);
            float p3 = fast_exp2(sacc[kt][3] - m_l);
            psum += (p0 + p1) + (p2 + p3);
            unsigned d0 = pack_bf16_trunc(p0, p1);
            unsigned d1 = pack_bf16_trunc(p2, p3);
            *(uint2*)&sP[w][l16][16 * kt + 4 * quad] = make_uint2(d0, d1);
        }
        l_l += psum;

        short8_t pf0 = *(const short8_t*)&sP[w][l16][quad * 8];
        short8_t pf1 = *(const short8_t*)&sP[w][l16][quad * 8 + 32];
        __builtin_amdgcn_s_setprio(1);
        #pragma unroll
        for (int dt = 0; dt < 4; ++dt) {
            short8_t vf0 = *(const short8_t*)&sVt[16 * dt + l16][quad * 8];
            short8_t vf1 = *(const short8_t*)&sVt[16 * dt + l16][quad * 8 + 32];
            oacc[dt] = __builtin_amdgcn_mfma_f32_16x16x32_bf16(pf0, vf0, oacc[dt], 0, 0, 0);
            oacc[dt] = __builtin_amdgcn_mfma_f32_16x16x32_bf16(pf1, vf1, oacc[dt], 0, 0, 0);
        }
        __builtin_amdgcn_s_setprio(0);
    }

    // reduce the quad-partial l across quads once
    l_l += __shfl_xor(l_l, 16);
    l_l += __shfl_xor(l_l, 32);

    #pragma unroll
    for (int r = 0; r < 4; ++r) {
        int m = quad * 4 + r;
        float lr = __shfl(l_l, quad * 4 + r);
        float inv = __builtin_amdgcn_rcpf(lr);
        #pragma unroll
        for (int dt = 0; dt < 4; ++dt)
            O[((size_t)b * T_SEQ + tq * 16 + m) * C_DIM + h * HD + 16 * dt + l16] =
                f2bs(oacc[dt][r] * inv);
    }
}

// ---------------------------------------------------------------------------
extern "C" void kernel_launch(void* const* d_in, const int* in_sizes, int n_in,
                              void* d_out, int out_size, void* d_ws, size_t ws_size,
                              hipStream_t stream)
{
    const float* x   = (const float*)d_in[0];
    const float* w_q = (const float*)d_in[1];
    const float* b_q = (const float*)d_in[2];
    const float* w_k = (const float*)d_in[3];
    const float* b_k = (const float*)d_in[4];
    const float* w_v = (const float*)d_in[5];
    const float* b_v = (const float*)d_in[6];
    const float* w_o = (const float*)d_in[7];
    const float* b_o = (const float*)d_in[8];
    float* out = (float*)d_out;

    char* ws = (char*)d_ws;
    short*  Xb   = (short*) (ws);                              // 8 MB
    short*  Ab   = (short*) (ws + ((size_t)8  << 20));         // 8 MB
    short*  QKVb = (short*) (ws + ((size_t)16 << 20));         // 12 MB
    short*  Wqkv = (short*) (ws + ((size_t)28 << 20));         // 3 MB
    short*  Wto  = (short*) (ws + ((size_t)31 << 20));         // 2 MB
    float*  Bqkv = (float*) (ws + ((size_t)33 << 20));         // 6 KB
    float2* Tab  = (float2*)(ws + ((size_t)33 << 20) + 8192);  // 512 KB
    short*  Vt   = (short*) (ws + ((size_t)34 << 20));         // 2 MB

    const int M = MTOK;   // 4096

    prep_kernel<<<6918, 256, 0, stream>>>(
        x, w_q, w_k, w_v, w_o, b_q, b_k, b_v, Xb, Wqkv, Wto, Bqkv, Tab);

    gemm_qkv<<<dim3(QKVW / 64, M / 128), 256, 0, stream>>>(
        Xb, Wqkv, Bqkv, Tab, QKVb, Vt);

    attn_mfma10<<<B_SZ * NKV * 128, 256, 0, stream>>>(QKVb, Vt, Ab);

    gemm_mfma_o<<<dim3(C_DIM / 64, M / 128), 256, 0, stream>>>(
        Ab, Wto, b_o, out, M, C_DIM, C_DIM);
}

// Round 2
// 168.103 us; speedup vs baseline: 1.0483x; 1.0136x over previous
//
#include <hip/hip_runtime.h>
#include <hip/hip_bf16.h>

typedef __hip_bfloat16 bf16;
typedef __attribute__((ext_vector_type(8))) short short8_t;
typedef __attribute__((ext_vector_type(4))) short short4_t;
typedef __attribute__((ext_vector_type(4))) float f32x4;

#define B_SZ   2
#define T_SEQ  2048
#define C_DIM  1024
#define NH     16
#define NKV    4
#define HD     64
#define QKVW   1536          // fused QKV row width (1024 Q | 256 K | 256 V)
#define MTOK   (B_SZ * T_SEQ)

#define LOG2_BASE_OVER_32 0.4152410118609203f
#define Q_SCALE 0.1803368801111204f   // 0.125 * log2(e)

__device__ __forceinline__ short f2bs(float f) {
    unsigned u = __float_as_uint(f);
    u += 0x7FFFu + ((u >> 16) & 1u);
    return (short)(u >> 16);
}
__device__ __forceinline__ short f2bs_trunc(float f) {
    return (short)(__float_as_uint(f) >> 16);
}
__device__ __forceinline__ float bs2f(short s) {
    unsigned u = ((unsigned)(unsigned short)s) << 16;
    return __uint_as_float(u);
}
// lane <-> lane^1 exchange, pure VALU (quad_perm [1,0,3,2])
__device__ __forceinline__ float dpp_xor1(float x) {
    return __int_as_float(
        __builtin_amdgcn_update_dpp(0, __float_as_int(x), 0xB1, 0xF, 0xF, true));
}
// bare v_exp_f32 (2^x). libm exp2f adds a denormal-guard wrapper (~8 VALU);
// here inputs are <= +8 or -inf, both exact on the raw instruction.
__device__ __forceinline__ float fast_exp2(float x) {
    float r;
    asm("v_exp_f32 %0, %1" : "=v"(r) : "v"(x));
    return r;
}
// pack hi16(lo), hi16(hi) -> one dword (two bf16, truncating) in 1 v_perm_b32
__device__ __forceinline__ unsigned pack_bf16_trunc(float lo, float hi) {
    return __builtin_amdgcn_perm(__float_as_uint(hi), __float_as_uint(lo),
                                 0x07060302u);
}

// ---------------------------------------------------------------------------
// Fused prep (unchanged): x->bf16, weight transposes, bias concat, RoPE table
// ---------------------------------------------------------------------------
__device__ __forceinline__ void transpose_tile(
    const float* __restrict__ W, short* __restrict__ Wt,
    int K, int N, int n0, int k0, int tid)
{
    __shared__ float tile[32][33];
    int tx = tid & 31, ty = tid >> 5;
    #pragma unroll
    for (int i = 0; i < 4; ++i)
        tile[ty + 8 * i][tx] = W[(size_t)(k0 + ty + 8 * i) * N + n0 + tx];
    __syncthreads();
    #pragma unroll
    for (int i = 0; i < 4; ++i)
        Wt[(size_t)(n0 + ty + 8 * i) * K + k0 + tx] = f2bs(tile[tx][ty + 8 * i]);
}

__global__ __launch_bounds__(256) void prep_kernel(
    const float* __restrict__ x,
    const float* __restrict__ w_q, const float* __restrict__ w_k,
    const float* __restrict__ w_v, const float* __restrict__ w_o,
    const float* __restrict__ b_q, const float* __restrict__ b_k,
    const float* __restrict__ b_v,
    short* __restrict__ Xb, short* __restrict__ Wqkv, short* __restrict__ Wto,
    float* __restrict__ Bqkv, float2* __restrict__ Tab)
{
    int blk = blockIdx.x, tid = threadIdx.x;
    if (blk < 4096) {
        int i = blk * 1024 + tid * 4;
        float4 v = *(const float4*)(x + i);
        short4_t o;
        o[0] = f2bs(v.x); o[1] = f2bs(v.y); o[2] = f2bs(v.z); o[3] = f2bs(v.w);
        *(short4_t*)(Xb + i) = o;
    } else if (blk < 5120) {
        int l = blk - 4096;
        transpose_tile(w_q, Wqkv, C_DIM, C_DIM, (l & 31) * 32, (l >> 5) * 32, tid);
    } else if (blk < 5376) {
        int l = blk - 5120;
        transpose_tile(w_k, Wqkv + (size_t)1024 * C_DIM, C_DIM, 256,
                       (l & 7) * 32, (l >> 3) * 32, tid);
    } else if (blk < 5632) {
        int l = blk - 5376;
        transpose_tile(w_v, Wqkv + (size_t)1280 * C_DIM, C_DIM, 256,
                       (l & 7) * 32, (l >> 3) * 32, tid);
    } else if (blk < 6656) {
        int l = blk - 5632;
        transpose_tile(w_o, Wto, C_DIM, C_DIM, (l & 31) * 32, (l >> 5) * 32, tid);
    } else if (blk < 6662) {
        int i = (blk - 6656) * 256 + tid;
        float v;
        if (i < 1024)      v = b_q[i];
        else if (i < 1280) v = b_k[i - 1024];
        else               v = b_v[i - 1280];
        Bqkv[i] = v;
    } else {
        int idx = (blk - 6662) * 256 + tid;
        int t = idx >> 5, i = idx & 31;
        float ang = (float)t * exp2f(-(float)i * LOG2_BASE_OVER_32);
        Tab[idx] = make_float2(cosf(ang), sinf(ang));
    }
}

// ---------------------------------------------------------------------------
// QKV GEMM, 128x64 tile (BM=128,BN=64,BK=32), double-buffered, 256 thr =
// 4 waves of 64x32. 768 blocks -> 3 blocks/CU. Fused epilogue:
//   n0<1024 (Q): +bias, RoPE, *Q_SCALE; 1024<=n0<1280 (K): +bias, RoPE;
//   n0>=1280 (V): +bias, transpose via LDS -> Vt[d][token].
// ---------------------------------------------------------------------------
__global__ __launch_bounds__(256) void gemm_qkv(
    const short* __restrict__ A, const short* __restrict__ Bt,
    const float* __restrict__ bias, const float2* __restrict__ Tab,
    short* __restrict__ QKVb, short* __restrict__ Vt)
{
    __shared__ __align__(16) short smem[15360];          // 30 KB
    short (*sA)[128][40] = (short(*)[128][40])smem;      // 2 x 128 x 40
    short (*sB)[64][40]  = (short(*)[64][40])(smem + 10240);

    const int K = C_DIM;
    int m0 = blockIdx.y * 128;
    int n0 = blockIdx.x * 64;
    int tid  = threadIdx.x;
    int w    = tid >> 6, lane = tid & 63;
    int quad = lane >> 4, l16 = lane & 15;
    int wm = w & 1, wn = w >> 1;

    f32x4 acc[4][2] = {};

    short8_t ra[2], rb;
    #pragma unroll
    for (int it = 0; it < 2; ++it) {
        int slot = tid + 256 * it, row = slot >> 2, g = (slot & 3) * 8;
        ra[it] = *(const short8_t*)(A + (size_t)(m0 + row) * K + g);
    }
    {
        int row = tid >> 2, g = (tid & 3) * 8;
        rb = *(const short8_t*)(Bt + (size_t)(n0 + row) * K + g);
    }

    int buf = 0;
    for (int k0 = 0; k0 < K; k0 += 32, buf ^= 1) {
        #pragma unroll
        for (int it = 0; it < 2; ++it) {
            int slot = tid + 256 * it, row = slot >> 2, g = (slot & 3) * 8;
            *(short8_t*)&sA[buf][row][g] = ra[it];
        }
        {
            int row = tid >> 2, g = (tid & 3) * 8;
            *(short8_t*)&sB[buf][row][g] = rb;
        }
        if (k0 + 32 < K) {
            #pragma unroll
            for (int it = 0; it < 2; ++it) {
                int slot = tid + 256 * it, row = slot >> 2, g = (slot & 3) * 8;
                ra[it] = *(const short8_t*)(A + (size_t)(m0 + row) * K + k0 + 32 + g);
            }
            int row = tid >> 2, g = (tid & 3) * 8;
            rb = *(const short8_t*)(Bt + (size_t)(n0 + row) * K + k0 + 32 + g);
        }
        __syncthreads();

        short8_t af[4], bfr[2];
        #pragma unroll
        for (int mt = 0; mt < 4; ++mt)
            af[mt] = *(const short8_t*)&sA[buf][wm * 64 + mt * 16 + l16][quad * 8];
        #pragma unroll
        for (int nt = 0; nt < 2; ++nt)
            bfr[nt] = *(const short8_t*)&sB[buf][wn * 32 + nt * 16 + l16][quad * 8];
        #pragma unroll
        for (int mt = 0; mt < 4; ++mt)
            #pragma unroll
            for (int nt = 0; nt < 2; ++nt)
                acc[mt][nt] = __builtin_amdgcn_mfma_f32_16x16x32_bf16(
                    af[mt], bfr[nt], acc[mt][nt], 0, 0, 0);
    }

    if (n0 < 1280) {
        // Q or K: bias + RoPE (+ Q_SCALE for Q)
        float scale = (n0 < 1024) ? Q_SCALE : 1.0f;
        float sgn   = (l16 & 1) ? 1.0f : -1.0f;
        #pragma unroll
        for (int nt = 0; nt < 2; ++nt) {
            int col = n0 + wn * 32 + nt * 16 + l16;
            int ip  = (col & 63) >> 1;
            float bv = bias[col];
            #pragma unroll
            for (int mt = 0; mt < 4; ++mt) {
                #pragma unroll
                for (int r = 0; r < 4; ++r) {
                    int row = m0 + wm * 64 + mt * 16 + quad * 4 + r;
                    float v = acc[mt][nt][r] + bv;
                    float po = dpp_xor1(v);
                    float2 cs = Tab[(row & (T_SEQ - 1)) * 32 + ip];
                    float res = (v * cs.x + sgn * po * cs.y) * scale;
                    QKVb[(size_t)row * QKVW + col] = f2bs(res);
                }
            }
        }
    } else {
        // V: bias + transpose via LDS -> Vt[d][token]
        __syncthreads();
        short (*sT)[136] = (short(*)[136])smem;    // 64 x 136 = 17.4 KB
        #pragma unroll
        for (int nt = 0; nt < 2; ++nt) {
            int col_l = wn * 32 + nt * 16 + l16;   // 0..63
            float bv = bias[n0 + col_l];
            #pragma unroll
            for (int mt = 0; mt < 4; ++mt)
                #pragma unroll
                for (int r = 0; r < 4; ++r)
                    sT[col_l][wm * 64 + mt * 16 + quad * 4 + r] =
                        f2bs(acc[mt][nt][r] + bv);
        }
        __syncthreads();
        int d0 = n0 - 1280;
        #pragma unroll
        for (int it = 0; it < 4; ++it) {
            int slot = tid + 256 * it;             // 64 dims x 16 segs
            int dl = slot >> 4, seg = (slot & 15) * 8;
            *(short8_t*)(Vt + (size_t)(d0 + dl) * MTOK + m0 + seg) =
                *(const short8_t*)&sT[dl][seg];
        }
    }
}

// ---------------------------------------------------------------------------
// O-projection GEMM, 128x64 tile (512 blocks -> 2/CU), fp32 out
// ---------------------------------------------------------------------------
__global__ __launch_bounds__(256) void gemm_mfma_o(
    const short* __restrict__ A, const short* __restrict__ Bt,
    const float* __restrict__ bias, float* __restrict__ C,
    int M, int N, int K)
{
    __shared__ __align__(16) short smem[15360];
    short (*sA)[128][40] = (short(*)[128][40])smem;
    short (*sB)[64][40]  = (short(*)[64][40])(smem + 10240);

    int m0 = blockIdx.y * 128;
    int n0 = blockIdx.x * 64;
    int tid  = threadIdx.x;
    int w    = tid >> 6, lane = tid & 63;
    int quad = lane >> 4, l16 = lane & 15;
    int wm = w & 1, wn = w >> 1;

    f32x4 acc[4][2] = {};

    short8_t ra[2], rb;
    #pragma unroll
    for (int it = 0; it < 2; ++it) {
        int slot = tid + 256 * it, row = slot >> 2, g = (slot & 3) * 8;
        ra[it] = *(const short8_t*)(A + (size_t)(m0 + row) * K + g);
    }
    {
        int row = tid >> 2, g = (tid & 3) * 8;
        rb = *(const short8_t*)(Bt + (size_t)(n0 + row) * K + g);
    }

    int buf = 0;
    for (int k0 = 0; k0 < K; k0 += 32, buf ^= 1) {
        #pragma unroll
        for (int it = 0; it < 2; ++it) {
            int slot = tid + 256 * it, row = slot >> 2, g = (slot & 3) * 8;
            *(short8_t*)&sA[buf][row][g] = ra[it];
        }
        {
            int row = tid >> 2, g = (tid & 3) * 8;
            *(short8_t*)&sB[buf][row][g] = rb;
        }
        if (k0 + 32 < K) {
            #pragma unroll
            for (int it = 0; it < 2; ++it) {
                int slot = tid + 256 * it, row = slot >> 2, g = (slot & 3) * 8;
                ra[it] = *(const short8_t*)(A + (size_t)(m0 + row) * K + k0 + 32 + g);
            }
            int row = tid >> 2, g = (tid & 3) * 8;
            rb = *(const short8_t*)(Bt + (size_t)(n0 + row) * K + k0 + 32 + g);
        }
        __syncthreads();

        short8_t af[4], bfr[2];
        #pragma unroll
        for (int mt = 0; mt < 4; ++mt)
            af[mt] = *(const short8_t*)&sA[buf][wm * 64 + mt * 16 + l16][quad * 8];
        #pragma unroll
        for (int nt = 0; nt < 2; ++nt)
            bfr[nt] = *(const short8_t*)&sB[buf][wn * 32 + nt * 16 + l16][quad * 8];
        #pragma unroll
        for (int mt = 0; mt < 4; ++mt)
            #pragma unroll
            for (int nt = 0; nt < 2; ++nt)
                acc[mt][nt] = __builtin_amdgcn_mfma_f32_16x16x32_bf16(
                    af[mt], bfr[nt], acc[mt][nt], 0, 0, 0);
    }

    #pragma unroll
    for (int mt = 0; mt < 4; ++mt) {
        #pragma unroll
        for (int nt = 0; nt < 2; ++nt) {
            int col = n0 + wn * 32 + nt * 16 + l16;
            float bv = bias[col];
            #pragma unroll
            for (int r = 0; r < 4; ++r) {
                int row = m0 + wm * 64 + mt * 16 + quad * 4 + r;
                C[(size_t)row * N + col] = acc[mt][nt][r] + bv;
            }
        }
    }
}

// ---------------------------------------------------------------------------
// MFMA flash attention v11:
//   - IN-REGISTER P: keys of the PV contraction are permuted (same perm on
//     P columns and V rows, so O is unchanged) so each lane's QK^T outputs
//     ARE its PV A-fragment. Zero cross-lane movement, sP eliminated, and
//     the softmax->PV LDS round-trip (4 writes + 2 reads + lgkm wait) gone.
//     perm: p bits [5][4:3][2][1:0] -> orig bits [5][2][4:3][1:0]; V rows
//     are staged at permuted positions (two b64 writes per 8 keys).
//   - double-buffered K/V staging: ONE barrier per chunk instead of two;
//     next-chunk global loads issued at top of iter, staged after PV.
//   - vf0 reads hoisted above softmax so PV LDS latency overlaps exp chain.
//   - retains: bare v_exp_f32, defer-max (THR=8), quad-partial l,
//     v_perm packs, s_setprio around MFMA clusters.
// ---------------------------------------------------------------------------
__global__ __launch_bounds__(256) void attn_mfma11(
    const short* __restrict__ QKV, const short* __restrict__ Vt,
    short* __restrict__ O)
{
    __shared__ __align__(16) short sK [2][64][72];
    __shared__ __align__(16) short sVt[2][64][72];

    const int tid  = threadIdx.x;
    const int w    = tid >> 6;
    const int lane = tid & 63;
    const int quad = lane >> 4;
    const int l16  = lane & 15;

    int blk = blockIdx.x;
    int grp = blk & 7;                 // (b,kvh)
    int tq  = 127 - (blk >> 3);        // long tiles first
    int kvh = grp & 3;
    int b   = grp >> 2;
    int h   = kvh * 4 + w;
    int ct  = tq >> 2;
    int tg  = tq * 16 + l16;

    // Q frags (already roped + scaled)
    const short* qptr = QKV + ((size_t)(b * T_SEQ) + tq * 16 + l16) * QKVW + h * HD;
    short8_t qf0 = *(const short8_t*)(qptr + quad * 8);
    short8_t qf1 = *(const short8_t*)(qptr + quad * 8 + 32);

    const short* kbase  = QKV + (size_t)b * T_SEQ * QKVW + 1024 + kvh * HD;
    const short* vtbase = Vt + (size_t)(kvh * HD) * MTOK + b * T_SEQ;

    float m_l = -INFINITY, l_l = 0.f;   // l_l is the QUAD-PARTIAL row sum
    f32x4 oacc[4];
    #pragma unroll
    for (int dt = 0; dt < 4; ++dt) oacc[dt] = (f32x4){0.f, 0.f, 0.f, 0.f};

    const int kkey = tid >> 3, kd = (tid & 7) * 8;
    const int vdim = tid >> 3;
    const int s8   = tid & 7;
    const int vseg = s8 * 8;
    // permuted base position for V staging: orig keys [8s..8s+7] land at
    // positions [P0..P0+3] and [P0+8..P0+11]
    const int P0 = ((s8 & 4) << 3) | ((s8 & 1) << 4) | ((s8 & 2) << 1);

    short8_t kr[2], vr[2];
    #pragma unroll
    for (int it = 0; it < 2; ++it) {
        kr[it] = *(const short8_t*)(kbase + (size_t)(kkey + 32 * it) * QKVW + kd);
        vr[it] = *(const short8_t*)(vtbase + (size_t)(vdim + 32 * it) * MTOK + vseg);
    }

    // prologue: stage chunk 0 into buffer 0
    #pragma unroll
    for (int it = 0; it < 2; ++it) {
        *(short8_t*)&sK[0][kkey + 32 * it][kd] = kr[it];
        union { short8_t v; short4_t h[2]; } u; u.v = vr[it];
        *(short4_t*)&sVt[0][vdim + 32 * it][P0]     = u.h[0];
        *(short4_t*)&sVt[0][vdim + 32 * it][P0 + 8] = u.h[1];
    }
    __syncthreads();

    for (int c = 0; c <= ct; ++c) {
        const int buf = c & 1;

        // issue next-chunk global loads early (latency hides under compute)
        if (c < ct) {
            int jn = (c + 1) * 64;
            #pragma unroll
            for (int it = 0; it < 2; ++it) {
                kr[it] = *(const short8_t*)(kbase + (size_t)(jn + kkey + 32 * it) * QKVW + kd);
                vr[it] = *(const short8_t*)(vtbase + (size_t)(vdim + 32 * it) * MTOK + jn + vseg);
            }
        }

        // S^T = K Q^T : rows = keys 16kt+quad*4+r, col = q = l16
        f32x4 sacc[4];
        __builtin_amdgcn_s_setprio(1);
        #pragma unroll
        for (int kt = 0; kt < 4; ++kt) {
            f32x4 z = {0.f, 0.f, 0.f, 0.f};
            short8_t kf0 = *(const short8_t*)&sK[buf][l16 + 16 * kt][quad * 8];
            short8_t kf1 = *(const short8_t*)&sK[buf][l16 + 16 * kt][quad * 8 + 32];
            z = __builtin_amdgcn_mfma_f32_16x16x32_bf16(kf0, qf0, z, 0, 0, 0);
            z = __builtin_amdgcn_mfma_f32_16x16x32_bf16(kf1, qf1, z, 0, 0, 0);
            sacc[kt] = z;
        }
        __builtin_amdgcn_s_setprio(0);

        // hoist first-half V fragments; LDS latency overlaps softmax VALU
        short8_t vf0[4];
        #pragma unroll
        for (int dt = 0; dt < 4; ++dt)
            vf0[dt] = *(const short8_t*)&sVt[buf][16 * dt + l16][quad * 8];

        if (c == ct) {
            int j0 = c * 64;
            #pragma unroll
            for (int kt = 0; kt < 4; ++kt)
                #pragma unroll
                for (int r = 0; r < 4; ++r)
                    if (j0 + 16 * kt + quad * 4 + r > tg) sacc[kt][r] = -INFINITY;
        }

        // local (quad-partial) max, nested triples -> v_max3
        float v0 = fmaxf(fmaxf(sacc[0][0], sacc[0][1]), fmaxf(sacc[0][2], sacc[0][3]));
        float v1 = fmaxf(fmaxf(sacc[1][0], sacc[1][1]), fmaxf(sacc[1][2], sacc[1][3]));
        float v2 = fmaxf(fmaxf(sacc[2][0], sacc[2][1]), fmaxf(sacc[2][2], sacc[2][3]));
        float v3 = fmaxf(fmaxf(sacc[3][0], sacc[3][1]), fmaxf(sacc[3][2], sacc[3][3]));
        float vloc = fmaxf(fmaxf(v0, v1), fmaxf(v2, v3));

        // defer-max: full (shuffle + rescale) update only when needed.
        // First chunk: m_l = -inf -> always updates.
        if (!__all(vloc <= m_l + 8.0f)) {
            float vmax = fmaxf(vloc, __shfl_xor(vloc, 16));
            vmax = fmaxf(vmax, __shfl_xor(vmax, 32));
            float mnew = fmaxf(m_l, vmax);
            float al = fast_exp2(m_l - mnew);      // exp2(-inf)=0 on chunk 0
            m_l = mnew;
            l_l *= al;
            #pragma unroll
            for (int r = 0; r < 4; ++r) {
                float alr = __shfl(al, quad * 4 + r);
                #pragma unroll
                for (int dt = 0; dt < 4; ++dt) oacc[dt][r] *= alr;
            }
        }

        // exp + pack P fragments IN REGISTER (keys permuted to match V)
        float psum = 0.f;
        unsigned pk0, pk1, pk2, pk3, pk4, pk5, pk6, pk7;
        {
            float p0 = fast_exp2(sacc[0][0] - m_l), p1 = fast_exp2(sacc[0][1] - m_l);
            float p2 = fast_exp2(sacc[0][2] - m_l), p3 = fast_exp2(sacc[0][3] - m_l);
            psum += (p0 + p1) + (p2 + p3);
            pk0 = pack_bf16_trunc(p0, p1); pk1 = pack_bf16_trunc(p2, p3);
        }
        {
            float p0 = fast_exp2(sacc[1][0] - m_l), p1 = fast_exp2(sacc[1][1] - m_l);
            float p2 = fast_exp2(sacc[1][2] - m_l), p3 = fast_exp2(sacc[1][3] - m_l);
            psum += (p0 + p1) + (p2 + p3);
            pk2 = pack_bf16_trunc(p0, p1); pk3 = pack_bf16_trunc(p2, p3);
        }
        {
            float p0 = fast_exp2(sacc[2][0] - m_l), p1 = fast_exp2(sacc[2][1] - m_l);
            float p2 = fast_exp2(sacc[2][2] - m_l), p3 = fast_exp2(sacc[2][3] - m_l);
            psum += (p0 + p1) + (p2 + p3);
            pk4 = pack_bf16_trunc(p0, p1); pk5 = pack_bf16_trunc(p2, p3);
        }
        {
            float p0 = fast_exp2(sacc[3][0] - m_l), p1 = fast_exp2(sacc[3][1] - m_l);
            float p2 = fast_exp2(sacc[3][2] - m_l), p3 = fast_exp2(sacc[3][3] - m_l);
            psum += (p0 + p1) + (p2 + p3);
            pk6 = pack_bf16_trunc(p0, p1); pk7 = pack_bf16_trunc(p2, p3);
        }
        l_l += psum;

        short8_t pf0, pf1;
        {
            union { unsigned u[4]; short8_t v; } fa, fb;
            fa.u[0] = pk0; fa.u[1] = pk1; fa.u[2] = pk2; fa.u[3] = pk3;
            fb.u[0] = pk4; fb.u[1] = pk5; fb.u[2] = pk6; fb.u[3] = pk7;
            pf0 = fa.v; pf1 = fb.v;
        }

        __builtin_amdgcn_s_setprio(1);
        #pragma unroll
        for (int dt = 0; dt < 4; ++dt) {
            short8_t vf1 = *(const short8_t*)&sVt[buf][16 * dt + l16][quad * 8 + 32];
            oacc[dt] = __builtin_amdgcn_mfma_f32_16x16x32_bf16(pf0, vf0[dt], oacc[dt], 0, 0, 0);
            oacc[dt] = __builtin_amdgcn_mfma_f32_16x16x32_bf16(pf1, vf1, oacc[dt], 0, 0, 0);
        }
        __builtin_amdgcn_s_setprio(0);

        // stage next chunk into the other buffer
        if (c < ct) {
            #pragma unroll
            for (int it = 0; it < 2; ++it) {
                *(short8_t*)&sK[buf ^ 1][kkey + 32 * it][kd] = kr[it];
                union { short8_t v; short4_t h[2]; } u; u.v = vr[it];
                *(short4_t*)&sVt[buf ^ 1][vdim + 32 * it][P0]     = u.h[0];
                *(short4_t*)&sVt[buf ^ 1][vdim + 32 * it][P0 + 8] = u.h[1];
            }
        }
        __syncthreads();
    }

    // reduce the quad-partial l across quads once
    l_l += __shfl_xor(l_l, 16);
    l_l += __shfl_xor(l_l, 32);

    #pragma unroll
    for (int r = 0; r < 4; ++r) {
        int m = quad * 4 + r;
        float lr = __shfl(l_l, quad * 4 + r);
        float inv = __builtin_amdgcn_rcpf(lr);
        #pragma unroll
        for (int dt = 0; dt < 4; ++dt)
            O[((size_t)b * T_SEQ + tq * 16 + m) * C_DIM + h * HD + 16 * dt + l16] =
                f2bs(oacc[dt][r] * inv);
    }
}

// ---------------------------------------------------------------------------
extern "C" void kernel_launch(void* const* d_in, const int* in_sizes, int n_in,
                              void* d_out, int out_size, void* d_ws, size_t ws_size,
                              hipStream_t stream)
{
    const float* x   = (const float*)d_in[0];
    const float* w_q = (const float*)d_in[1];
    const float* b_q = (const float*)d_in[2];
    const float* w_k = (const float*)d_in[3];
    const float* b_k = (const float*)d_in[4];
    const float* w_v = (const float*)d_in[5];
    const float* b_v = (const float*)d_in[6];
    const float* w_o = (const float*)d_in[7];
    const float* b_o = (const float*)d_in[8];
    float* out = (float*)d_out;

    char* ws = (char*)d_ws;
    short*  Xb   = (short*) (ws);                              // 8 MB
    short*  Ab   = (short*) (ws + ((size_t)8  << 20));         // 8 MB
    short*  QKVb = (short*) (ws + ((size_t)16 << 20));         // 12 MB
    short*  Wqkv = (short*) (ws + ((size_t)28 << 20));         // 3 MB
    short*  Wto  = (short*) (ws + ((size_t)31 << 20));         // 2 MB
    float*  Bqkv = (float*) (ws + ((size_t)33 << 20));         // 6 KB
    float2* Tab  = (float2*)(ws + ((size_t)33 << 20) + 8192);  // 512 KB
    short*  Vt   = (short*) (ws + ((size_t)34 << 20));         // 2 MB

    const int M = MTOK;   // 4096

    prep_kernel<<<6918, 256, 0, stream>>>(
        x, w_q, w_k, w_v, w_o, b_q, b_k, b_v, Xb, Wqkv, Wto, Bqkv, Tab);

    gemm_qkv<<<dim3(QKVW / 64, M / 128), 256, 0, stream>>>(
        Xb, Wqkv, Bqkv, Tab, QKVb, Vt);

    attn_mfma11<<<B_SZ * NKV * 128, 256, 0, stream>>>(QKVb, Vt, Ab);

    gemm_mfma_o<<<dim3(C_DIM / 64, M / 128), 256, 0, stream>>>(
        Ab, Wto, b_o, out, M, C_DIM, C_DIM);
}

// Round 3
// 164.246 us; speedup vs baseline: 1.0729x; 1.0235x over previous
//
#include <hip/hip_runtime.h>
#include <hip/hip_bf16.h>

typedef __hip_bfloat16 bf16;
typedef __attribute__((ext_vector_type(8))) short short8_t;
typedef __attribute__((ext_vector_type(4))) short short4_t;
typedef __attribute__((ext_vector_type(4))) float f32x4;

#define B_SZ   2
#define T_SEQ  2048
#define C_DIM  1024
#define NH     16
#define NKV    4
#define HD     64
#define QKVW   1536          // fused QKV row width (1024 Q | 256 K | 256 V)
#define MTOK   (B_SZ * T_SEQ)

#define LOG2_BASE_OVER_32 0.4152410118609203f
#define Q_SCALE 0.1803368801111204f   // 0.125 * log2(e)

__device__ __forceinline__ short f2bs(float f) {
    unsigned u = __float_as_uint(f);
    u += 0x7FFFu + ((u >> 16) & 1u);
    return (short)(u >> 16);
}
__device__ __forceinline__ short f2bs_trunc(float f) {
    return (short)(__float_as_uint(f) >> 16);
}
__device__ __forceinline__ float bs2f(short s) {
    unsigned u = ((unsigned)(unsigned short)s) << 16;
    return __uint_as_float(u);
}
// lane <-> lane^1 exchange, pure VALU (quad_perm [1,0,3,2])
__device__ __forceinline__ float dpp_xor1(float x) {
    return __int_as_float(
        __builtin_amdgcn_update_dpp(0, __float_as_int(x), 0xB1, 0xF, 0xF, true));
}
// bare v_exp_f32 (2^x)
__device__ __forceinline__ float fast_exp2(float x) {
    float r;
    asm("v_exp_f32 %0, %1" : "=v"(r) : "v"(x));
    return r;
}
// pack hi16(lo), hi16(hi) -> one dword (two bf16, truncating) in 1 v_perm_b32
__device__ __forceinline__ unsigned pack_bf16_trunc(float lo, float hi) {
    return __builtin_amdgcn_perm(__float_as_uint(hi), __float_as_uint(lo),
                                 0x07060302u);
}
// direct HBM -> LDS, 16B per lane. LDS dest = (wave-uniform base) + lane*16.
__device__ __forceinline__ void gload_lds16(const short* g, short* l) {
    __builtin_amdgcn_global_load_lds(
        (const __attribute__((address_space(1))) void*)g,
        (__attribute__((address_space(3))) void*)l, 16, 0, 0);
}

// ---------------------------------------------------------------------------
// Fused prep (unchanged): x->bf16, weight transposes, bias concat, RoPE table
// ---------------------------------------------------------------------------
__device__ __forceinline__ void transpose_tile(
    const float* __restrict__ W, short* __restrict__ Wt,
    int K, int N, int n0, int k0, int tid)
{
    __shared__ float tile[32][33];
    int tx = tid & 31, ty = tid >> 5;
    #pragma unroll
    for (int i = 0; i < 4; ++i)
        tile[ty + 8 * i][tx] = W[(size_t)(k0 + ty + 8 * i) * N + n0 + tx];
    __syncthreads();
    #pragma unroll
    for (int i = 0; i < 4; ++i)
        Wt[(size_t)(n0 + ty + 8 * i) * K + k0 + tx] = f2bs(tile[tx][ty + 8 * i]);
}

__global__ __launch_bounds__(256) void prep_kernel(
    const float* __restrict__ x,
    const float* __restrict__ w_q, const float* __restrict__ w_k,
    const float* __restrict__ w_v, const float* __restrict__ w_o,
    const float* __restrict__ b_q, const float* __restrict__ b_k,
    const float* __restrict__ b_v,
    short* __restrict__ Xb, short* __restrict__ Wqkv, short* __restrict__ Wto,
    float* __restrict__ Bqkv, float2* __restrict__ Tab)
{
    int blk = blockIdx.x, tid = threadIdx.x;
    if (blk < 4096) {
        int i = blk * 1024 + tid * 4;
        float4 v = *(const float4*)(x + i);
        short4_t o;
        o[0] = f2bs(v.x); o[1] = f2bs(v.y); o[2] = f2bs(v.z); o[3] = f2bs(v.w);
        *(short4_t*)(Xb + i) = o;
    } else if (blk < 5120) {
        int l = blk - 4096;
        transpose_tile(w_q, Wqkv, C_DIM, C_DIM, (l & 31) * 32, (l >> 5) * 32, tid);
    } else if (blk < 5376) {
        int l = blk - 5120;
        transpose_tile(w_k, Wqkv + (size_t)1024 * C_DIM, C_DIM, 256,
                       (l & 7) * 32, (l >> 3) * 32, tid);
    } else if (blk < 5632) {
        int l = blk - 5376;
        transpose_tile(w_v, Wqkv + (size_t)1280 * C_DIM, C_DIM, 256,
                       (l & 7) * 32, (l >> 3) * 32, tid);
    } else if (blk < 6656) {
        int l = blk - 5632;
        transpose_tile(w_o, Wto, C_DIM, C_DIM, (l & 31) * 32, (l >> 5) * 32, tid);
    } else if (blk < 6662) {
        int i = (blk - 6656) * 256 + tid;
        float v;
        if (i < 1024)      v = b_q[i];
        else if (i < 1280) v = b_k[i - 1024];
        else               v = b_v[i - 1280];
        Bqkv[i] = v;
    } else {
        int idx = (blk - 6662) * 256 + tid;
        int t = idx >> 5, i = idx & 31;
        float ang = (float)t * exp2f(-(float)i * LOG2_BASE_OVER_32);
        Tab[idx] = make_float2(cosf(ang), sinf(ang));
    }
}

// ---------------------------------------------------------------------------
// QKV GEMM v2: same 128x64 tile / 4-wave / grid / epilogues as before, but the
// K-loop is rebuilt in the m97 pattern: BK=64, single-buffered LDS (24 KB ->
// 6 blocks/CU cap, 3 resident), staging via global_load_lds (16B/lane,
// HBM->LDS direct), XOR-swizzled via pre-swizzled GLOBAL source + swizzled
// ds_read (conflict-free b128 fragment reads, no padding).
// ---------------------------------------------------------------------------
__global__ __launch_bounds__(256) void gemm_qkv(
    const short* __restrict__ A, const short* __restrict__ Bt,
    const float* __restrict__ bias, const float2* __restrict__ Tab,
    short* __restrict__ QKVb, short* __restrict__ Vt)
{
    __shared__ __align__(16) short smem[12288];     // 24 KB: A 128x64 | B 64x64
    short* sA0 = smem;                              // 8192 shorts
    short* sB0 = smem + 8192;                       // 4096 shorts

    const int K = C_DIM;
    int m0 = blockIdx.y * 128;
    int n0 = blockIdx.x * 64;
    int tid  = threadIdx.x;
    int w    = tid >> 6, lane = tid & 63;
    int quad = lane >> 4, l16 = lane & 15;
    int wm = w & 1, wn = w >> 1;

    f32x4 acc[4][2] = {};

    for (int k0 = 0; k0 < K; k0 += 64) {
        // stage A tile: 128 rows x 64 shorts; source col pre-swizzled
        #pragma unroll
        for (int it = 0; it < 4; ++it) {
            int i = (w * 4 + it) * 64 + lane;        // granule slot 0..1023
            int row = i >> 3, p = i & 7;
            int gc = k0 + ((p ^ (row & 7)) << 3);
            gload_lds16(A + (size_t)(m0 + row) * K + gc, sA0 + (w * 4 + it) * 512);
        }
        // stage B tile: 64 rows x 64 shorts
        #pragma unroll
        for (int it = 0; it < 2; ++it) {
            int i = (w * 2 + it) * 64 + lane;        // granule slot 0..511
            int row = i >> 3, p = i & 7;
            int gc = k0 + ((p ^ (row & 7)) << 3);
            gload_lds16(Bt + (size_t)(n0 + row) * K + gc, sB0 + (w * 2 + it) * 512);
        }
        __syncthreads();                              // drains vmcnt

        #pragma unroll
        for (int ks = 0; ks < 2; ++ks) {
            short8_t af[4], bf[2];
            #pragma unroll
            for (int mt = 0; mt < 4; ++mt) {
                int r = wm * 64 + mt * 16 + l16;
                int g = ks * 4 + quad;
                af[mt] = *(const short8_t*)&sA0[r * 64 + ((g ^ (r & 7)) << 3)];
            }
            #pragma unroll
            for (int nt = 0; nt < 2; ++nt) {
                int r = wn * 32 + nt * 16 + l16;
                int g = ks * 4 + quad;
                bf[nt] = *(const short8_t*)&sB0[r * 64 + ((g ^ (r & 7)) << 3)];
            }
            #pragma unroll
            for (int mt = 0; mt < 4; ++mt)
                #pragma unroll
                for (int nt = 0; nt < 2; ++nt)
                    acc[mt][nt] = __builtin_amdgcn_mfma_f32_16x16x32_bf16(
                        af[mt], bf[nt], acc[mt][nt], 0, 0, 0);
        }
        __syncthreads();
    }

    if (n0 < 1280) {
        // Q or K: bias + RoPE (+ Q_SCALE for Q)
        float scale = (n0 < 1024) ? Q_SCALE : 1.0f;
        float sgn   = (l16 & 1) ? 1.0f : -1.0f;
        #pragma unroll
        for (int nt = 0; nt < 2; ++nt) {
            int col = n0 + wn * 32 + nt * 16 + l16;
            int ip  = (col & 63) >> 1;
            float bv = bias[col];
            #pragma unroll
            for (int mt = 0; mt < 4; ++mt) {
                #pragma unroll
                for (int r = 0; r < 4; ++r) {
                    int row = m0 + wm * 64 + mt * 16 + quad * 4 + r;
                    float v = acc[mt][nt][r] + bv;
                    float po = dpp_xor1(v);
                    float2 cs = Tab[(row & (T_SEQ - 1)) * 32 + ip];
                    float res = (v * cs.x + sgn * po * cs.y) * scale;
                    QKVb[(size_t)row * QKVW + col] = f2bs(res);
                }
            }
        }
    } else {
        // V: bias + transpose via LDS -> Vt[d][token]
        short (*sT)[136] = (short(*)[136])smem;    // 64 x 136 = 8704 shorts
        #pragma unroll
        for (int nt = 0; nt < 2; ++nt) {
            int col_l = wn * 32 + nt * 16 + l16;   // 0..63
            float bv = bias[n0 + col_l];
            #pragma unroll
            for (int mt = 0; mt < 4; ++mt)
                #pragma unroll
                for (int r = 0; r < 4; ++r)
                    sT[col_l][wm * 64 + mt * 16 + quad * 4 + r] =
                        f2bs(acc[mt][nt][r] + bv);
        }
        __syncthreads();
        int d0 = n0 - 1280;
        #pragma unroll
        for (int it = 0; it < 4; ++it) {
            int slot = tid + 256 * it;             // 64 dims x 16 segs
            int dl = slot >> 4, seg = (slot & 15) * 8;
            *(short8_t*)(Vt + (size_t)(d0 + dl) * MTOK + m0 + seg) =
                *(const short8_t*)&sT[dl][seg];
        }
    }
}

// ---------------------------------------------------------------------------
// O-projection GEMM v2: same m97-pattern K-loop, fp32 out epilogue unchanged
// ---------------------------------------------------------------------------
__global__ __launch_bounds__(256) void gemm_mfma_o(
    const short* __restrict__ A, const short* __restrict__ Bt,
    const float* __restrict__ bias, float* __restrict__ C,
    int M, int N, int K)
{
    __shared__ __align__(16) short smem[12288];
    short* sA0 = smem;
    short* sB0 = smem + 8192;

    int m0 = blockIdx.y * 128;
    int n0 = blockIdx.x * 64;
    int tid  = threadIdx.x;
    int w    = tid >> 6, lane = tid & 63;
    int quad = lane >> 4, l16 = lane & 15;
    int wm = w & 1, wn = w >> 1;

    f32x4 acc[4][2] = {};

    for (int k0 = 0; k0 < K; k0 += 64) {
        #pragma unroll
        for (int it = 0; it < 4; ++it) {
            int i = (w * 4 + it) * 64 + lane;
            int row = i >> 3, p = i & 7;
            int gc = k0 + ((p ^ (row & 7)) << 3);
            gload_lds16(A + (size_t)(m0 + row) * K + gc, sA0 + (w * 4 + it) * 512);
        }
        #pragma unroll
        for (int it = 0; it < 2; ++it) {
            int i = (w * 2 + it) * 64 + lane;
            int row = i >> 3, p = i & 7;
            int gc = k0 + ((p ^ (row & 7)) << 3);
            gload_lds16(Bt + (size_t)(n0 + row) * K + gc, sB0 + (w * 2 + it) * 512);
        }
        __syncthreads();

        #pragma unroll
        for (int ks = 0; ks < 2; ++ks) {
            short8_t af[4], bf[2];
            #pragma unroll
            for (int mt = 0; mt < 4; ++mt) {
                int r = wm * 64 + mt * 16 + l16;
                int g = ks * 4 + quad;
                af[mt] = *(const short8_t*)&sA0[r * 64 + ((g ^ (r & 7)) << 3)];
            }
            #pragma unroll
            for (int nt = 0; nt < 2; ++nt) {
                int r = wn * 32 + nt * 16 + l16;
                int g = ks * 4 + quad;
                bf[nt] = *(const short8_t*)&sB0[r * 64 + ((g ^ (r & 7)) << 3)];
            }
            #pragma unroll
            for (int mt = 0; mt < 4; ++mt)
                #pragma unroll
                for (int nt = 0; nt < 2; ++nt)
                    acc[mt][nt] = __builtin_amdgcn_mfma_f32_16x16x32_bf16(
                        af[mt], bf[nt], acc[mt][nt], 0, 0, 0);
        }
        __syncthreads();
    }

    #pragma unroll
    for (int mt = 0; mt < 4; ++mt) {
        #pragma unroll
        for (int nt = 0; nt < 2; ++nt) {
            int col = n0 + wn * 32 + nt * 16 + l16;
            float bv = bias[col];
            #pragma unroll
            for (int r = 0; r < 4; ++r) {
                int row = m0 + wm * 64 + mt * 16 + quad * 4 + r;
                C[(size_t)row * N + col] = acc[mt][nt][r] + bv;
            }
        }
    }
}

// ---------------------------------------------------------------------------
// MFMA flash attention v11 (unchanged this round)
// ---------------------------------------------------------------------------
__global__ __launch_bounds__(256) void attn_mfma11(
    const short* __restrict__ QKV, const short* __restrict__ Vt,
    short* __restrict__ O)
{
    __shared__ __align__(16) short sK [2][64][72];
    __shared__ __align__(16) short sVt[2][64][72];

    const int tid  = threadIdx.x;
    const int w    = tid >> 6;
    const int lane = tid & 63;
    const int quad = lane >> 4;
    const int l16  = lane & 15;

    int blk = blockIdx.x;
    int grp = blk & 7;                 // (b,kvh)
    int tq  = 127 - (blk >> 3);        // long tiles first
    int kvh = grp & 3;
    int b   = grp >> 2;
    int h   = kvh * 4 + w;
    int ct  = tq >> 2;
    int tg  = tq * 16 + l16;

    const short* qptr = QKV + ((size_t)(b * T_SEQ) + tq * 16 + l16) * QKVW + h * HD;
    short8_t qf0 = *(const short8_t*)(qptr + quad * 8);
    short8_t qf1 = *(const short8_t*)(qptr + quad * 8 + 32);

    const short* kbase  = QKV + (size_t)b * T_SEQ * QKVW + 1024 + kvh * HD;
    const short* vtbase = Vt + (size_t)(kvh * HD) * MTOK + b * T_SEQ;

    float m_l = -INFINITY, l_l = 0.f;   // l_l is the QUAD-PARTIAL row sum
    f32x4 oacc[4];
    #pragma unroll
    for (int dt = 0; dt < 4; ++dt) oacc[dt] = (f32x4){0.f, 0.f, 0.f, 0.f};

    const int kkey = tid >> 3, kd = (tid & 7) * 8;
    const int vdim = tid >> 3;
    const int s8   = tid & 7;
    const int vseg = s8 * 8;
    const int P0 = ((s8 & 4) << 3) | ((s8 & 1) << 4) | ((s8 & 2) << 1);

    short8_t kr[2], vr[2];
    #pragma unroll
    for (int it = 0; it < 2; ++it) {
        kr[it] = *(const short8_t*)(kbase + (size_t)(kkey + 32 * it) * QKVW + kd);
        vr[it] = *(const short8_t*)(vtbase + (size_t)(vdim + 32 * it) * MTOK + vseg);
    }

    #pragma unroll
    for (int it = 0; it < 2; ++it) {
        *(short8_t*)&sK[0][kkey + 32 * it][kd] = kr[it];
        union { short8_t v; short4_t h[2]; } u; u.v = vr[it];
        *(short4_t*)&sVt[0][vdim + 32 * it][P0]     = u.h[0];
        *(short4_t*)&sVt[0][vdim + 32 * it][P0 + 8] = u.h[1];
    }
    __syncthreads();

    for (int c = 0; c <= ct; ++c) {
        const int buf = c & 1;

        if (c < ct) {
            int jn = (c + 1) * 64;
            #pragma unroll
            for (int it = 0; it < 2; ++it) {
                kr[it] = *(const short8_t*)(kbase + (size_t)(jn + kkey + 32 * it) * QKVW + kd);
                vr[it] = *(const short8_t*)(vtbase + (size_t)(vdim + 32 * it) * MTOK + jn + vseg);
            }
        }

        f32x4 sacc[4];
        __builtin_amdgcn_s_setprio(1);
        #pragma unroll
        for (int kt = 0; kt < 4; ++kt) {
            f32x4 z = {0.f, 0.f, 0.f, 0.f};
            short8_t kf0 = *(const short8_t*)&sK[buf][l16 + 16 * kt][quad * 8];
            short8_t kf1 = *(const short8_t*)&sK[buf][l16 + 16 * kt][quad * 8 + 32];
            z = __builtin_amdgcn_mfma_f32_16x16x32_bf16(kf0, qf0, z, 0, 0, 0);
            z = __builtin_amdgcn_mfma_f32_16x16x32_bf16(kf1, qf1, z, 0, 0, 0);
            sacc[kt] = z;
        }
        __builtin_amdgcn_s_setprio(0);

        short8_t vf0[4];
        #pragma unroll
        for (int dt = 0; dt < 4; ++dt)
            vf0[dt] = *(const short8_t*)&sVt[buf][16 * dt + l16][quad * 8];

        if (c == ct) {
            int j0 = c * 64;
            #pragma unroll
            for (int kt = 0; kt < 4; ++kt)
                #pragma unroll
                for (int r = 0; r < 4; ++r)
                    if (j0 + 16 * kt + quad * 4 + r > tg) sacc[kt][r] = -INFINITY;
        }

        float v0 = fmaxf(fmaxf(sacc[0][0], sacc[0][1]), fmaxf(sacc[0][2], sacc[0][3]));
        float v1 = fmaxf(fmaxf(sacc[1][0], sacc[1][1]), fmaxf(sacc[1][2], sacc[1][3]));
        float v2 = fmaxf(fmaxf(sacc[2][0], sacc[2][1]), fmaxf(sacc[2][2], sacc[2][3]));
        float v3 = fmaxf(fmaxf(sacc[3][0], sacc[3][1]), fmaxf(sacc[3][2], sacc[3][3]));
        float vloc = fmaxf(fmaxf(v0, v1), fmaxf(v2, v3));

        if (!__all(vloc <= m_l + 8.0f)) {
            float vmax = fmaxf(vloc, __shfl_xor(vloc, 16));
            vmax = fmaxf(vmax, __shfl_xor(vmax, 32));
            float mnew = fmaxf(m_l, vmax);
            float al = fast_exp2(m_l - mnew);
            m_l = mnew;
            l_l *= al;
            #pragma unroll
            for (int r = 0; r < 4; ++r) {
                float alr = __shfl(al, quad * 4 + r);
                #pragma unroll
                for (int dt = 0; dt < 4; ++dt) oacc[dt][r] *= alr;
            }
        }

        float psum = 0.f;
        unsigned pk0, pk1, pk2, pk3, pk4, pk5, pk6, pk7;
        {
            float p0 = fast_exp2(sacc[0][0] - m_l), p1 = fast_exp2(sacc[0][1] - m_l);
            float p2 = fast_exp2(sacc[0][2] - m_l), p3 = fast_exp2(sacc[0][3] - m_l);
            psum += (p0 + p1) + (p2 + p3);
            pk0 = pack_bf16_trunc(p0, p1); pk1 = pack_bf16_trunc(p2, p3);
        }
        {
            float p0 = fast_exp2(sacc[1][0] - m_l), p1 = fast_exp2(sacc[1][1] - m_l);
            float p2 = fast_exp2(sacc[1][2] - m_l), p3 = fast_exp2(sacc[1][3] - m_l);
            psum += (p0 + p1) + (p2 + p3);
            pk2 = pack_bf16_trunc(p0, p1); pk3 = pack_bf16_trunc(p2, p3);
        }
        {
            float p0 = fast_exp2(sacc[2][0] - m_l), p1 = fast_exp2(sacc[2][1] - m_l);
            float p2 = fast_exp2(sacc[2][2] - m_l), p3 = fast_exp2(sacc[2][3] - m_l);
            psum += (p0 + p1) + (p2 + p3);
            pk4 = pack_bf16_trunc(p0, p1); pk5 = pack_bf16_trunc(p2, p3);
        }
        {
            float p0 = fast_exp2(sacc[3][0] - m_l), p1 = fast_exp2(sacc[3][1] - m_l);
            float p2 = fast_exp2(sacc[3][2] - m_l), p3 = fast_exp2(sacc[3][3] - m_l);
            psum += (p0 + p1) + (p2 + p3);
            pk6 = pack_bf16_trunc(p0, p1); pk7 = pack_bf16_trunc(p2, p3);
        }
        l_l += psum;

        short8_t pf0, pf1;
        {
            union { unsigned u[4]; short8_t v; } fa, fb;
            fa.u[0] = pk0; fa.u[1] = pk1; fa.u[2] = pk2; fa.u[3] = pk3;
            fb.u[0] = pk4; fb.u[1] = pk5; fb.u[2] = pk6; fb.u[3] = pk7;
            pf0 = fa.v; pf1 = fb.v;
        }

        __builtin_amdgcn_s_setprio(1);
        #pragma unroll
        for (int dt = 0; dt < 4; ++dt) {
            short8_t vf1 = *(const short8_t*)&sVt[buf][16 * dt + l16][quad * 8 + 32];
            oacc[dt] = __builtin_amdgcn_mfma_f32_16x16x32_bf16(pf0, vf0[dt], oacc[dt], 0, 0, 0);
            oacc[dt] = __builtin_amdgcn_mfma_f32_16x16x32_bf16(pf1, vf1, oacc[dt], 0, 0, 0);
        }
        __builtin_amdgcn_s_setprio(0);

        if (c < ct) {
            #pragma unroll
            for (int it = 0; it < 2; ++it) {
                *(short8_t*)&sK[buf ^ 1][kkey + 32 * it][kd] = kr[it];
                union { short8_t v; short4_t h[2]; } u; u.v = vr[it];
                *(short4_t*)&sVt[buf ^ 1][vdim + 32 * it][P0]     = u.h[0];
                *(short4_t*)&sVt[buf ^ 1][vdim + 32 * it][P0 + 8] = u.h[1];
            }
        }
        __syncthreads();
    }

    l_l += __shfl_xor(l_l, 16);
    l_l += __shfl_xor(l_l, 32);

    #pragma unroll
    for (int r = 0; r < 4; ++r) {
        int m = quad * 4 + r;
        float lr = __shfl(l_l, quad * 4 + r);
        float inv = __builtin_amdgcn_rcpf(lr);
        #pragma unroll
        for (int dt = 0; dt < 4; ++dt)
            O[((size_t)b * T_SEQ + tq * 16 + m) * C_DIM + h * HD + 16 * dt + l16] =
                f2bs(oacc[dt][r] * inv);
    }
}

// ---------------------------------------------------------------------------
extern "C" void kernel_launch(void* const* d_in, const int* in_sizes, int n_in,
                              void* d_out, int out_size, void* d_ws, size_t ws_size,
                              hipStream_t stream)
{
    const float* x   = (const float*)d_in[0];
    const float* w_q = (const float*)d_in[1];
    const float* b_q = (const float*)d_in[2];
    const float* w_k = (const float*)d_in[3];
    const float* b_k = (const float*)d_in[4];
    const float* w_v = (const float*)d_in[5];
    const float* b_v = (const float*)d_in[6];
    const float* w_o = (const float*)d_in[7];
    const float* b_o = (const float*)d_in[8];
    float* out = (float*)d_out;

    char* ws = (char*)d_ws;
    short*  Xb   = (short*) (ws);                              // 8 MB
    short*  Ab   = (short*) (ws + ((size_t)8  << 20));         // 8 MB
    short*  QKVb = (short*) (ws + ((size_t)16 << 20));         // 12 MB
    short*  Wqkv = (short*) (ws + ((size_t)28 << 20));         // 3 MB
    short*  Wto  = (short*) (ws + ((size_t)31 << 20));         // 2 MB
    float*  Bqkv = (float*) (ws + ((size_t)33 << 20));         // 6 KB
    float2* Tab  = (float2*)(ws + ((size_t)33 << 20) + 8192);  // 512 KB
    short*  Vt   = (short*) (ws + ((size_t)34 << 20));         // 2 MB

    const int M = MTOK;   // 4096

    prep_kernel<<<6918, 256, 0, stream>>>(
        x, w_q, w_k, w_v, w_o, b_q, b_k, b_v, Xb, Wqkv, Wto, Bqkv, Tab);

    gemm_qkv<<<dim3(QKVW / 64, M / 128), 256, 0, stream>>>(
        Xb, Wqkv, Bqkv, Tab, QKVb, Vt);

    attn_mfma11<<<B_SZ * NKV * 128, 256, 0, stream>>>(QKVb, Vt, Ab);

    gemm_mfma_o<<<dim3(C_DIM / 64, M / 128), 256, 0, stream>>>(
        Ab, Wto, b_o, out, M, C_DIM, C_DIM);
}